// Round 1
// baseline (7292.897 us; speedup 1.0000x reference)
//
#include <hip/hip_runtime.h>

// Problem constants (B=1 throughout)
#define TT 8
#define HH 24
#define WW 24
#define NN (TT*HH*WW)   // 4608 spatial points
#define CIN 256

// ---------------------------------------------------------------------------
// Direct 3x3x3 conv, pad=1, NCDHW. One thread = one spatial point, COB output
// channels register-blocked. Taps precomputed once (clamped index + 0/1 mask).
// Weight reads are wave-uniform -> scalar loads.
// ---------------------------------------------------------------------------
template<int COB, bool RELU>
__global__ __launch_bounds__(256) void conv3d_k(
    const float* __restrict__ x, const float* __restrict__ w,
    const float* __restrict__ bias, float* __restrict__ y, int Cout)
{
    const int n   = blockIdx.x * 256 + threadIdx.x;   // spatial point
    const int co0 = blockIdx.y * COB;                 // first output channel
    const int t   = n / (HH*WW);
    const int hw  = n - t*(HH*WW);
    const int h   = hw / WW;
    const int wq  = hw - h*WW;

    int   idx27[27];
    float msk27[27];
    #pragma unroll
    for (int dt = 0; dt < 3; ++dt)
    #pragma unroll
    for (int dh = 0; dh < 3; ++dh)
    #pragma unroll
    for (int dw = 0; dw < 3; ++dw) {
        const int k  = (dt*3+dh)*3+dw;
        const int tt = t+dt-1, hh = h+dh-1, ww = wq+dw-1;
        const bool v = (tt>=0)&&(tt<TT)&&(hh>=0)&&(hh<HH)&&(ww>=0)&&(ww<WW);
        idx27[k] = v ? ((tt*HH+hh)*WW+ww) : 0;   // clamp invalid to 0 (safe addr)
        msk27[k] = v ? 1.f : 0.f;
    }

    float acc[COB];
    #pragma unroll
    for (int c = 0; c < COB; ++c) acc[c] = 0.f;

    for (int ci = 0; ci < CIN; ++ci) {
        const float* xp = x + (size_t)ci*NN;
        float xv[27];
        #pragma unroll
        for (int k = 0; k < 27; ++k) xv[k] = xp[idx27[k]] * msk27[k];
        #pragma unroll
        for (int c = 0; c < COB; ++c) {
            const int co = min(co0 + c, Cout - 1);     // clamped: safe reads, store guarded
            const float* wp = w + ((size_t)co*CIN + ci)*27;
            #pragma unroll
            for (int k = 0; k < 27; ++k)
                acc[c] = fmaf(wp[k], xv[k], acc[c]);
        }
    }

    #pragma unroll
    for (int c = 0; c < COB; ++c) {
        if (co0 + c < Cout) {
            float r = acc[c] + bias[co0 + c];
            if (RELU) r = fmaxf(r, 0.f);
            y[(size_t)(co0 + c)*NN + n] = r;
        }
    }
}

// ---------------------------------------------------------------------------
// Deformable conv: per (n, k) compute 8 trilinear corners once (registers),
// then loop cin: sample (8 gathers) and accumulate into COB output channels.
// offsets layout: channel c = k*3 + d, d in {t,h,w}; k = (dt+1)*9+(dh+1)*3+(dw+1).
// ---------------------------------------------------------------------------
template<int COB>
__global__ __launch_bounds__(256) void deform_k(
    const float* __restrict__ x, const float* __restrict__ off,
    const float* __restrict__ w2, const float* __restrict__ bias,
    float* __restrict__ out)
{
    const int n   = blockIdx.x * 256 + threadIdx.x;
    const int co0 = blockIdx.y * COB;
    const int t   = n / (HH*WW);
    const int hw  = n - t*(HH*WW);
    const int h   = hw / WW;
    const int wq  = hw - h*WW;

    float acc[COB];
    #pragma unroll
    for (int c = 0; c < COB; ++c) acc[c] = 0.f;

    for (int k = 0; k < 27; ++k) {
        const int ki = k/9, kj = (k/3)%3, kl = k%3;
        const float pt = (float)(t  + ki - 1) + off[(size_t)(k*3+0)*NN + n];
        const float ph = (float)(h  + kj - 1) + off[(size_t)(k*3+1)*NN + n];
        const float pw = (float)(wq + kl - 1) + off[(size_t)(k*3+2)*NN + n];
        const float ft = floorf(pt), fh = floorf(ph), fw = floorf(pw);
        const float at = pt-ft, ah = ph-fh, aw = pw-fw;
        const int it = (int)ft, ih = (int)fh, iw = (int)fw;

        int   cidx[8];
        float cwt[8];
        #pragma unroll
        for (int dt = 0; dt < 2; ++dt)
        #pragma unroll
        for (int dh = 0; dh < 2; ++dh)
        #pragma unroll
        for (int dw = 0; dw < 2; ++dw) {
            const int c  = (dt*2+dh)*2+dw;
            const int ti = it+dt, hi = ih+dh, wi = iw+dw;
            const bool v = (ti>=0)&&(ti<TT)&&(hi>=0)&&(hi<HH)&&(wi>=0)&&(wi<WW);
            const float wgt = (dt ? at : 1.f-at)*(dh ? ah : 1.f-ah)*(dw ? aw : 1.f-aw);
            cwt[c] = v ? wgt : 0.f;
            const int tc = min(max(ti,0),TT-1), hc = min(max(hi,0),HH-1), wc = min(max(wi,0),WW-1);
            cidx[c] = (tc*HH+hc)*WW+wc;
        }

        for (int ci = 0; ci < CIN; ++ci) {
            const float* xp = x + (size_t)ci*NN;
            float s = 0.f;
            #pragma unroll
            for (int c = 0; c < 8; ++c) s = fmaf(cwt[c], xp[cidx[c]], s);
            #pragma unroll
            for (int cc = 0; cc < COB; ++cc)
                acc[cc] = fmaf(w2[((size_t)(co0+cc)*CIN + ci)*27 + k], s, acc[cc]);
        }
    }

    #pragma unroll
    for (int cc = 0; cc < COB; ++cc)
        out[(size_t)(co0+cc)*NN + n] = acc[cc] + bias[co0+cc];
}

// ---------------------------------------------------------------------------
extern "C" void kernel_launch(void* const* d_in, const int* in_sizes, int n_in,
                              void* d_out, int out_size, void* d_ws, size_t ws_size,
                              hipStream_t stream)
{
    const float* x   = (const float*)d_in[0];
    const float* l1w = (const float*)d_in[1];
    const float* l1b = (const float*)d_in[2];
    const float* l2w = (const float*)d_in[3];
    const float* l2b = (const float*)d_in[4];
    const float* l3w = (const float*)d_in[5];
    const float* l3b = (const float*)d_in[6];
    const float* dfw = (const float*)d_in[7];
    const float* dfb = (const float*)d_in[8];
    const float* c3w = (const float*)d_in[9];
    const float* c3b = (const float*)d_in[10];
    float* out = (float*)d_out;

    // workspace: h1, h2, h3 (256*4608 each), offsets (81*4608). ~15.7 MB total.
    float* h1   = (float*)d_ws;
    float* h2   = h1 + (size_t)CIN*NN;
    float* h3   = h2 + (size_t)CIN*NN;
    float* offs = h3 + (size_t)CIN*NN;

    const dim3 blk(256);
    conv3d_k<8,true ><<<dim3(NN/256, 256/8),      blk, 0, stream>>>(x,  l1w, l1b, h1,   256);
    conv3d_k<8,true ><<<dim3(NN/256, 256/8),      blk, 0, stream>>>(h1, l2w, l2b, h2,   256);
    conv3d_k<8,true ><<<dim3(NN/256, 256/8),      blk, 0, stream>>>(h2, l3w, l3b, h3,   256);
    conv3d_k<8,false><<<dim3(NN/256, (81+7)/8),   blk, 0, stream>>>(h3, dfw, dfb, offs,  81);
    deform_k<16>     <<<dim3(NN/256, 256/16),     blk, 0, stream>>>(x,  offs, c3w, c3b, out);
}

// Round 2
// 1451.237 us; speedup vs baseline: 5.0253x; 5.0253x over previous
//
#include <hip/hip_runtime.h>

#define TT 8
#define HH 24
#define WW 24
#define NN 4608            // T*H*W
#define CIN 256
#define GUARD 640          // >= max |tap shift| (601), multiple of 16
#define NNP (NN + 2*GUARD) // padded spatial row: 5888
#define KDIM 6912          // 27 taps * 256 ci
#define BK 64
#define LDA 72             // LDS row stride (elems): 64 + 8 pad -> 144B rows
#define KTILES 108         // KDIM / BK

typedef short short8 __attribute__((ext_vector_type(8)));
typedef float f32x4  __attribute__((ext_vector_type(4)));

#define MFMA16 __builtin_amdgcn_mfma_f32_16x16x32_bf16

__device__ __forceinline__ short f2bf(float f) {       // RNE f32 -> bf16 bits
    unsigned u = __float_as_uint(f);
    unsigned r = u + 0x7fffu + ((u >> 16) & 1u);
    return (short)(r >> 16);
}

// ---------------------------------------------------------------- utility
__global__ void pad_copy_k(const float* __restrict__ x, float* __restrict__ xp) {
    int gid = blockIdx.x * 256 + threadIdx.x;           // 256*NN threads
    int ci = gid / NN, n = gid - ci * NN;
    xp[(size_t)ci * NNP + GUARD + n] = x[gid];
}

// wrb[o][k*256+ci] = bf16(w[o][ci][k]); rows o>=Cout zeroed.
__global__ void repack_w_k(const float* __restrict__ w, short* __restrict__ dst, int Cout) {
    int o = blockIdx.x, ci = threadIdx.x;
    short* drow = dst + (size_t)o * KDIM + ci;
    if (o < Cout) {
        const float* src = w + ((size_t)o * CIN + ci) * 27;
        #pragma unroll
        for (int k = 0; k < 27; ++k) drow[(size_t)k * CIN] = f2bf(src[k]);
    } else {
        #pragma unroll
        for (int k = 0; k < 27; ++k) drow[(size_t)k * CIN] = 0;
    }
}

// mask64[k][wn]: bit b = tap k valid at spatial point n = wn*64+b
__global__ void mask_k(unsigned long long* __restrict__ m) {
    int id = blockIdx.x * 256 + threadIdx.x;
    if (id >= 27 * 72) return;
    int k = id / 72, wn = id - k * 72;
    int dt = k / 9 - 1, dh = (k % 9) / 3 - 1, dw = k % 3 - 1;
    unsigned long long word = 0;
    for (int b = 0; b < 64; ++b) {
        int n = wn * 64 + b;
        int t = n / (HH * WW), r = n % (HH * WW), h = r / WW, w2 = r % WW;
        int tt = t + dt, hh = h + dh, ww = w2 + dw;
        if (tt >= 0 && tt < TT && hh >= 0 && hh < HH && ww >= 0 && ww < WW)
            word |= 1ull << b;
    }
    m[id] = word;
}

// trilinear tables from offsets: per (k, n): 8 clamped indices + 8 masked weights
__global__ void table_k(const float* __restrict__ offs, int* __restrict__ tidx,
                        float* __restrict__ twt) {
    int id = blockIdx.x * 256 + threadIdx.x;            // 27*NN threads
    int k = id / NN, n = id - k * NN;
    int t = n / (HH * WW), r = n % (HH * WW), h = r / WW, w2 = r % WW;
    int ki = k / 9, kj = (k % 9) / 3, kl = k % 3;
    float pt = (float)(t + ki - 1) + offs[(size_t)(k * 3 + 0) * NN + n];
    float ph = (float)(h + kj - 1) + offs[(size_t)(k * 3 + 1) * NN + n];
    float pw = (float)(w2 + kl - 1) + offs[(size_t)(k * 3 + 2) * NN + n];
    float ft = floorf(pt), fh = floorf(ph), fw = floorf(pw);
    float at = pt - ft, ah = ph - fh, aw = pw - fw;
    int it = (int)ft, ih = (int)fh, iw = (int)fw;
    #pragma unroll
    for (int dt = 0; dt < 2; ++dt)
    #pragma unroll
    for (int dh = 0; dh < 2; ++dh)
    #pragma unroll
    for (int dw = 0; dw < 2; ++dw) {
        int c = (dt * 2 + dh) * 2 + dw;
        int ti = it + dt, hi = ih + dh, wi = iw + dw;
        bool v = (ti >= 0) && (ti < TT) && (hi >= 0) && (hi < HH) && (wi >= 0) && (wi < WW);
        float wgt = (dt ? at : 1.f - at) * (dh ? ah : 1.f - ah) * (dw ? aw : 1.f - aw);
        int tc = min(max(ti, 0), TT - 1), hc = min(max(hi, 0), HH - 1), wc = min(max(wi, 0), WW - 1);
        tidx[(size_t)(k * 8 + c) * NN + n] = (tc * HH + hc) * WW + wc;
        twt [(size_t)(k * 8 + c) * NN + n] = v ? wgt : 0.f;
    }
}

// ---------------------------------------------------------------- conv GEMM
// C[co][n] = sum_{k,ci} wrb[co][k*256+ci] * src[ci][n + delta(k)] * mask(k,n)
template<bool RELU, bool PADOUT>
__global__ __launch_bounds__(256) void gemm_conv(
    const float* __restrict__ src,            // padded [CIN][NNP]
    const short* __restrict__ wrb,            // bf16 [Cpad][KDIM], K = k*256+ci
    const unsigned long long* __restrict__ mask64,
    const float* __restrict__ bias, float* __restrict__ dst, int Cout)
{
    __shared__ short Ap[64 * LDA];            // patches [n][kk]
    __shared__ short Bw[64 * LDA];            // weights [co][kk]
    const int tid = threadIdx.x;
    const int lane = tid & 63, wave = tid >> 6;
    const int n0 = blockIdx.x * 64, co0 = blockIdx.y * 64;
    const int n_l = tid & 63, grp = tid >> 6;     // A-stage: 1 n x 16 ci
    const int co_l = tid >> 2, ch = tid & 3;      // B-stage: 1 co x 16 kk
    const int n_off = (wave & 1) * 32, co_off = (wave >> 1) * 32;
    const int lm = lane & 15, lq = lane >> 4;

    f32x4 acc[2][2] = {};

    const float* abase = src + GUARD + n0 + n_l;
    const short* bbase = wrb + (size_t)(co0 + co_l) * KDIM + ch * 16;

    for (int kt = 0; kt < KTILES; ++kt) {
        const int k = kt >> 2, ci0 = (kt & 3) * 64;
        const int dt = k / 9 - 1, dh = (k % 9) / 3 - 1, dw = k % 3 - 1;
        const int delta = (dt * HH + dh) * WW + dw;
        const unsigned long long word = mask64[k * 72 + blockIdx.x];
        const bool keep = (word >> n_l) & 1;
        // A stage: 16 coalesced dword loads (one per ci), mask, cvt, 2x b128 LDS write
        {
            const float* s0 = abase + delta + (size_t)(ci0 + grp * 16) * NNP;
            short8 p0, p1;
            #pragma unroll
            for (int j = 0; j < 8; ++j) {
                float f = s0[(size_t)j * NNP];
                p0[j] = f2bf(keep ? f : 0.f);
            }
            #pragma unroll
            for (int j = 0; j < 8; ++j) {
                float f = s0[(size_t)(j + 8) * NNP];
                p1[j] = f2bf(keep ? f : 0.f);
            }
            short8* dA = (short8*)&Ap[n_l * LDA + grp * 16];
            dA[0] = p0; dA[1] = p1;
        }
        // B stage: 2x b128 global read, 2x b128 LDS write
        {
            const short8* g = (const short8*)(bbase + (size_t)kt * BK);
            short8 b0 = g[0], b1 = g[1];
            short8* dB = (short8*)&Bw[co_l * LDA + ch * 16];
            dB[0] = b0; dB[1] = b1;
        }
        __syncthreads();
        #pragma unroll
        for (int ks = 0; ks < 2; ++ks) {
            short8 a0 = *(const short8*)&Ap[(n_off + lm) * LDA + ks * 32 + lq * 8];
            short8 a1 = *(const short8*)&Ap[(n_off + 16 + lm) * LDA + ks * 32 + lq * 8];
            short8 b0 = *(const short8*)&Bw[(co_off + lm) * LDA + ks * 32 + lq * 8];
            short8 b1 = *(const short8*)&Bw[(co_off + 16 + lm) * LDA + ks * 32 + lq * 8];
            acc[0][0] = MFMA16(a0, b0, acc[0][0], 0, 0, 0);
            acc[0][1] = MFMA16(a0, b1, acc[0][1], 0, 0, 0);
            acc[1][0] = MFMA16(a1, b0, acc[1][0], 0, 0, 0);
            acc[1][1] = MFMA16(a1, b1, acc[1][1], 0, 0, 0);
        }
        __syncthreads();
    }
    #pragma unroll
    for (int fn = 0; fn < 2; ++fn)
    #pragma unroll
    for (int fc = 0; fc < 2; ++fc) {
        int co = co0 + co_off + fc * 16 + lm;
        if (co < Cout) {
            int n = n0 + n_off + fn * 16 + lq * 4;
            float bv = bias[co];
            f32x4 v = acc[fn][fc];
            #pragma unroll
            for (int r2 = 0; r2 < 4; ++r2) {
                float f = v[r2] + bv;
                if (RELU) f = fmaxf(f, 0.f);
                v[r2] = f;
            }
            float* o = PADOUT ? (dst + (size_t)co * NNP + GUARD + n)
                              : (dst + (size_t)co * NN + n);
            *(f32x4*)o = v;
        }
    }
}

// ---------------------------------------------------------------- deform GEMM
// C[co][n] = sum_{k,ci} wrb[co][k*256+ci] * sample(ci, k, n)
__global__ __launch_bounds__(256) void gemm_deform(
    const float* __restrict__ x,              // original x [CIN][NN]
    const short* __restrict__ wrb,            // bf16 c3d weights repacked
    const int* __restrict__ tidx, const float* __restrict__ twt,
    const float* __restrict__ bias, float* __restrict__ out)
{
    __shared__ short Ap[64 * LDA];
    __shared__ short Bw[64 * LDA];
    const int tid = threadIdx.x;
    const int lane = tid & 63, wave = tid >> 6;
    const int n0 = blockIdx.x * 64, co0 = blockIdx.y * 64;
    const int n_l = tid & 63, grp = tid >> 6;
    const int co_l = tid >> 2, ch = tid & 3;
    const int n_off = (wave & 1) * 32, co_off = (wave >> 1) * 32;
    const int lm = lane & 15, lq = lane >> 4;
    const int n_g = n0 + n_l;

    f32x4 acc[2][2] = {};
    const short* bbase = wrb + (size_t)(co0 + co_l) * KDIM + ch * 16;

    for (int kt = 0; kt < KTILES; ++kt) {
        const int k = kt >> 2, ci0 = (kt & 3) * 64;
        // A stage: trilinear sample 16 channels at this thread's n
        {
            int   ic[8]; float wc[8];
            #pragma unroll
            for (int c = 0; c < 8; ++c) {
                ic[c] = tidx[(size_t)(k * 8 + c) * NN + n_g];
                wc[c] = twt [(size_t)(k * 8 + c) * NN + n_g];
            }
            short8 p0, p1;
            #pragma unroll
            for (int j = 0; j < 8; ++j) {
                const float* xr = x + (size_t)(ci0 + grp * 16 + j) * NN;
                float s = 0.f;
                #pragma unroll
                for (int c = 0; c < 8; ++c) s = fmaf(wc[c], xr[ic[c]], s);
                p0[j] = f2bf(s);
            }
            #pragma unroll
            for (int j = 0; j < 8; ++j) {
                const float* xr = x + (size_t)(ci0 + grp * 16 + 8 + j) * NN;
                float s = 0.f;
                #pragma unroll
                for (int c = 0; c < 8; ++c) s = fmaf(wc[c], xr[ic[c]], s);
                p1[j] = f2bf(s);
            }
            short8* dA = (short8*)&Ap[n_l * LDA + grp * 16];
            dA[0] = p0; dA[1] = p1;
        }
        {
            const short8* g = (const short8*)(bbase + (size_t)kt * BK);
            short8 b0 = g[0], b1 = g[1];
            short8* dB = (short8*)&Bw[co_l * LDA + ch * 16];
            dB[0] = b0; dB[1] = b1;
        }
        __syncthreads();
        #pragma unroll
        for (int ks = 0; ks < 2; ++ks) {
            short8 a0 = *(const short8*)&Ap[(n_off + lm) * LDA + ks * 32 + lq * 8];
            short8 a1 = *(const short8*)&Ap[(n_off + 16 + lm) * LDA + ks * 32 + lq * 8];
            short8 b0 = *(const short8*)&Bw[(co_off + lm) * LDA + ks * 32 + lq * 8];
            short8 b1 = *(const short8*)&Bw[(co_off + 16 + lm) * LDA + ks * 32 + lq * 8];
            acc[0][0] = MFMA16(a0, b0, acc[0][0], 0, 0, 0);
            acc[0][1] = MFMA16(a0, b1, acc[0][1], 0, 0, 0);
            acc[1][0] = MFMA16(a1, b0, acc[1][0], 0, 0, 0);
            acc[1][1] = MFMA16(a1, b1, acc[1][1], 0, 0, 0);
        }
        __syncthreads();
    }
    #pragma unroll
    for (int fn = 0; fn < 2; ++fn)
    #pragma unroll
    for (int fc = 0; fc < 2; ++fc) {
        int co = co0 + co_off + fc * 16 + lm;
        int n = n0 + n_off + fn * 16 + lq * 4;
        float bv = bias[co];
        f32x4 v = acc[fn][fc];
        #pragma unroll
        for (int r2 = 0; r2 < 4; ++r2) v[r2] += bv;
        *(f32x4*)(out + (size_t)co * NN + n) = v;
    }
}

// ----------------------------------------------------------------
extern "C" void kernel_launch(void* const* d_in, const int* in_sizes, int n_in,
                              void* d_out, int out_size, void* d_ws, size_t ws_size,
                              hipStream_t stream)
{
    const float* x   = (const float*)d_in[0];
    const float* l1w = (const float*)d_in[1];
    const float* l1b = (const float*)d_in[2];
    const float* l2w = (const float*)d_in[3];
    const float* l2b = (const float*)d_in[4];
    const float* l3w = (const float*)d_in[5];
    const float* l3b = (const float*)d_in[6];
    const float* dfw = (const float*)d_in[7];
    const float* dfb = (const float*)d_in[8];
    const float* c3w = (const float*)d_in[9];
    const float* c3b = (const float*)d_in[10];
    float* out = (float*)d_out;

    char* p = (char*)d_ws;
    float* xpad = (float*)p; p += (size_t)CIN * NNP * 4;
    float* h1   = (float*)p; p += (size_t)CIN * NNP * 4;
    float* h2   = (float*)p; p += (size_t)CIN * NNP * 4;
    float* h3   = (float*)p; p += (size_t)CIN * NNP * 4;
    short* wrb1 = (short*)p; p += (size_t)CIN * KDIM * 2;
    short* wrb2 = (short*)p; p += (size_t)CIN * KDIM * 2;
    short* wrb3 = (short*)p; p += (size_t)CIN * KDIM * 2;
    short* wrbc = (short*)p; p += (size_t)CIN * KDIM * 2;
    short* wrbd = (short*)p; p += (size_t)128 * KDIM * 2;   // 81 rows used, rest 0
    float* offs = (float*)p; p += (size_t)81 * NN * 4;
    int*   tidx = (int*)p;   p += (size_t)27 * 8 * NN * 4;
    float* twt  = (float*)p; p += (size_t)27 * 8 * NN * 4;
    unsigned long long* m64 = (unsigned long long*)p;

    // zero the pads of xpad/h1/h2/h3 (interiors are fully overwritten)
    hipMemsetAsync(d_ws, 0, (size_t)4 * CIN * NNP * 4, stream);

    pad_copy_k<<<dim3(CIN * NN / 256), dim3(256), 0, stream>>>(x, xpad);
    repack_w_k<<<dim3(256), dim3(256), 0, stream>>>(l1w, wrb1, 256);
    repack_w_k<<<dim3(256), dim3(256), 0, stream>>>(l2w, wrb2, 256);
    repack_w_k<<<dim3(256), dim3(256), 0, stream>>>(l3w, wrb3, 256);
    repack_w_k<<<dim3(256), dim3(256), 0, stream>>>(c3w, wrbc, 256);
    repack_w_k<<<dim3(128), dim3(256), 0, stream>>>(dfw, wrbd, 81);
    mask_k<<<dim3(8), dim3(256), 0, stream>>>(m64);

    gemm_conv<true,  true ><<<dim3(72, 4), dim3(256), 0, stream>>>(xpad, wrb1, m64, l1b, h1, 256);
    gemm_conv<true,  true ><<<dim3(72, 4), dim3(256), 0, stream>>>(h1,   wrb2, m64, l2b, h2, 256);
    gemm_conv<true,  true ><<<dim3(72, 4), dim3(256), 0, stream>>>(h2,   wrb3, m64, l3b, h3, 256);
    gemm_conv<false, false><<<dim3(72, 2), dim3(256), 0, stream>>>(h3,   wrbd, m64, dfb, offs, 81);

    table_k<<<dim3(27 * NN / 256), dim3(256), 0, stream>>>(offs, tidx, twt);
    gemm_deform<<<dim3(72, 4), dim3(256), 0, stream>>>(x, wrbc, tidx, twt, c3b, out);
}

// Round 3
// 562.045 us; speedup vs baseline: 12.9757x; 2.5821x over previous
//
#include <hip/hip_runtime.h>

#define TT 8
#define HH 24
#define WW 24
#define NN 4608            // T*H*W
#define CIN 256
#define GUARD 640          // >= max |tap shift| (601), multiple of 16
#define NNP (NN + 2*GUARD) // padded spatial row: 5888
#define KDIM 6912          // 27 taps * 256 ci
#define BK 64
#define LDA 72             // LDS row stride (elems): 64 + 8 pad -> 144B rows
#define KTILES 108         // KDIM / BK

typedef short short8 __attribute__((ext_vector_type(8)));
typedef short short4v __attribute__((ext_vector_type(4)));
typedef float f32x4  __attribute__((ext_vector_type(4)));

#define MFMA16 __builtin_amdgcn_mfma_f32_16x16x32_bf16

__device__ __forceinline__ short f2bf(float f) {       // RNE f32 -> bf16 bits
    unsigned u = __float_as_uint(f);
    unsigned r = u + 0x7fffu + ((u >> 16) & 1u);
    return (short)(r >> 16);
}

// ---------------------------------------------------------------- utility
__global__ void pad_copy_k(const float* __restrict__ x, float* __restrict__ xp) {
    int gid = blockIdx.x * 256 + threadIdx.x;           // 256*NN threads
    int ci = gid / NN, n = gid - ci * NN;
    xp[(size_t)ci * NNP + GUARD + n] = x[gid];
}

// x[ci][n] -> xT[n][ci], 64x64 LDS tiles
__global__ __launch_bounds__(256) void transpose_k(const float* __restrict__ x,
                                                   float* __restrict__ xT) {
    __shared__ float T[64][65];
    const int lane = threadIdx.x & 63, wave = threadIdx.x >> 6;
    const int n0 = blockIdx.x * 64, ci0 = blockIdx.y * 64;
    #pragma unroll
    for (int j = 0; j < 16; ++j) {
        int ci_l = wave * 16 + j;
        T[ci_l][lane] = x[(size_t)(ci0 + ci_l) * NN + n0 + lane];
    }
    __syncthreads();
    #pragma unroll
    for (int j = 0; j < 16; ++j) {
        int n_l = wave * 16 + j;
        xT[(size_t)(n0 + n_l) * 256 + ci0 + lane] = T[lane][n_l];
    }
}

// wrb[o][k*256+ci] = bf16(w[o][ci][k]); rows o>=Cout zeroed.
__global__ void repack_w_k(const float* __restrict__ w, short* __restrict__ dst, int Cout) {
    int o = blockIdx.x, ci = threadIdx.x;
    short* drow = dst + (size_t)o * KDIM + ci;
    if (o < Cout) {
        const float* src = w + ((size_t)o * CIN + ci) * 27;
        #pragma unroll
        for (int k = 0; k < 27; ++k) drow[(size_t)k * CIN] = f2bf(src[k]);
    } else {
        #pragma unroll
        for (int k = 0; k < 27; ++k) drow[(size_t)k * CIN] = 0;
    }
}

// mask64[k][wn]: bit b = tap k valid at spatial point n = wn*64+b
__global__ void mask_k(unsigned long long* __restrict__ m) {
    int id = blockIdx.x * 256 + threadIdx.x;
    if (id >= 27 * 72) return;
    int k = id / 72, wn = id - k * 72;
    int dt = k / 9 - 1, dh = (k % 9) / 3 - 1, dw = k % 3 - 1;
    unsigned long long word = 0;
    for (int b = 0; b < 64; ++b) {
        int n = wn * 64 + b;
        int t = n / (HH * WW), r = n % (HH * WW), h = r / WW, w2 = r % WW;
        int tt = t + dt, hh = h + dh, ww = w2 + dw;
        if (tt >= 0 && tt < TT && hh >= 0 && hh < HH && ww >= 0 && ww < WW)
            word |= 1ull << b;
    }
    m[id] = word;
}

// ---------------------------------------------------------------- sampler
// S[k][n][ci] = bf16( sum_c w_c(k,n) * xT[idx_c(k,n)][ci] ), ci fastest.
// One wave per (k,n): lanes cover 256 channels as f32x4; 8 coalesced row loads.
__global__ __launch_bounds__(256) void sample_k(
    const float* __restrict__ xT, const float* __restrict__ offs,
    short* __restrict__ S)
{
    const int k = blockIdx.y, n0 = blockIdx.x * 64;
    const int lane = threadIdx.x & 63, wave = threadIdx.x >> 6;
    const int ki = k / 9, kj = (k % 9) / 3, kl = k % 3;

    for (int i = 0; i < 16; ++i) {
        const int n = n0 + wave * 16 + i;
        const int t = n / (HH * WW), r = n % (HH * WW), h = r / WW, w2 = r % WW;
        const float pt = (float)(t  + ki - 1) + offs[(size_t)(k * 3 + 0) * NN + n];
        const float ph = (float)(h  + kj - 1) + offs[(size_t)(k * 3 + 1) * NN + n];
        const float pw = (float)(w2 + kl - 1) + offs[(size_t)(k * 3 + 2) * NN + n];
        const float ft = floorf(pt), fh = floorf(ph), fw = floorf(pw);
        const float at = pt - ft, ah = ph - fh, aw = pw - fw;
        const int it = (int)ft, ih = (int)fh, iw = (int)fw;

        f32x4 s = {0.f, 0.f, 0.f, 0.f};
        #pragma unroll
        for (int dt = 0; dt < 2; ++dt)
        #pragma unroll
        for (int dh = 0; dh < 2; ++dh)
        #pragma unroll
        for (int dw = 0; dw < 2; ++dw) {
            const int ti = it + dt, hi = ih + dh, wi = iw + dw;
            const bool v = (ti >= 0) && (ti < TT) && (hi >= 0) && (hi < HH) && (wi >= 0) && (wi < WW);
            float wgt = (dt ? at : 1.f - at) * (dh ? ah : 1.f - ah) * (dw ? aw : 1.f - aw);
            wgt = v ? wgt : 0.f;
            const int tc = min(max(ti, 0), TT - 1), hc = min(max(hi, 0), HH - 1), wc = min(max(wi, 0), WW - 1);
            const int idx = (tc * HH + hc) * WW + wc;
            const f32x4 vv = *(const f32x4*)(xT + (size_t)idx * 256 + lane * 4);
            #pragma unroll
            for (int q = 0; q < 4; ++q) s[q] = fmaf(wgt, vv[q], s[q]);
        }
        short4v o;
        #pragma unroll
        for (int q = 0; q < 4; ++q) o[q] = f2bf(s[q]);
        *(short4v*)(S + ((size_t)k * NN + n) * 256 + lane * 4) = o;
    }
}

// ---------------------------------------------------------------- conv GEMM
// C[co][n] = sum_{k,ci} wrb[co][k*256+ci] * src[ci][n + delta(k)] * mask(k,n)
template<bool RELU, bool PADOUT>
__global__ __launch_bounds__(256) void gemm_conv(
    const float* __restrict__ src,            // padded [CIN][NNP]
    const short* __restrict__ wrb,            // bf16 [Cpad][KDIM], K = k*256+ci
    const unsigned long long* __restrict__ mask64,
    const float* __restrict__ bias, float* __restrict__ dst, int Cout)
{
    __shared__ short Ap[64 * LDA];            // patches [n][kk]
    __shared__ short Bw[64 * LDA];            // weights [co][kk]
    const int tid = threadIdx.x;
    const int lane = tid & 63, wave = tid >> 6;
    const int n0 = blockIdx.x * 64, co0 = blockIdx.y * 64;
    const int n_l = tid & 63, grp = tid >> 6;     // A-stage: 1 n x 16 ci
    const int co_l = tid >> 2, ch = tid & 3;      // B-stage: 1 co x 16 kk
    const int n_off = (wave & 1) * 32, co_off = (wave >> 1) * 32;
    const int lm = lane & 15, lq = lane >> 4;

    f32x4 acc[2][2] = {};

    const float* abase = src + GUARD + n0 + n_l;
    const short* bbase = wrb + (size_t)(co0 + co_l) * KDIM + ch * 16;

    for (int kt = 0; kt < KTILES; ++kt) {
        const int k = kt >> 2, ci0 = (kt & 3) * 64;
        const int dt = k / 9 - 1, dh = (k % 9) / 3 - 1, dw = k % 3 - 1;
        const int delta = (dt * HH + dh) * WW + dw;
        const unsigned long long word = mask64[k * 72 + blockIdx.x];
        const bool keep = (word >> n_l) & 1;
        {
            const float* s0 = abase + delta + (size_t)(ci0 + grp * 16) * NNP;
            short8 p0, p1;
            #pragma unroll
            for (int j = 0; j < 8; ++j) {
                float f = s0[(size_t)j * NNP];
                p0[j] = f2bf(keep ? f : 0.f);
            }
            #pragma unroll
            for (int j = 0; j < 8; ++j) {
                float f = s0[(size_t)(j + 8) * NNP];
                p1[j] = f2bf(keep ? f : 0.f);
            }
            short8* dA = (short8*)&Ap[n_l * LDA + grp * 16];
            dA[0] = p0; dA[1] = p1;
        }
        {
            const short8* g = (const short8*)(bbase + (size_t)kt * BK);
            short8 b0 = g[0], b1 = g[1];
            short8* dB = (short8*)&Bw[co_l * LDA + ch * 16];
            dB[0] = b0; dB[1] = b1;
        }
        __syncthreads();
        #pragma unroll
        for (int ks = 0; ks < 2; ++ks) {
            short8 a0 = *(const short8*)&Ap[(n_off + lm) * LDA + ks * 32 + lq * 8];
            short8 a1 = *(const short8*)&Ap[(n_off + 16 + lm) * LDA + ks * 32 + lq * 8];
            short8 b0 = *(const short8*)&Bw[(co_off + lm) * LDA + ks * 32 + lq * 8];
            short8 b1 = *(const short8*)&Bw[(co_off + 16 + lm) * LDA + ks * 32 + lq * 8];
            acc[0][0] = MFMA16(a0, b0, acc[0][0], 0, 0, 0);
            acc[0][1] = MFMA16(a0, b1, acc[0][1], 0, 0, 0);
            acc[1][0] = MFMA16(a1, b0, acc[1][0], 0, 0, 0);
            acc[1][1] = MFMA16(a1, b1, acc[1][1], 0, 0, 0);
        }
        __syncthreads();
    }
    #pragma unroll
    for (int fn = 0; fn < 2; ++fn)
    #pragma unroll
    for (int fc = 0; fc < 2; ++fc) {
        int co = co0 + co_off + fc * 16 + lm;
        if (co < Cout) {
            int n = n0 + n_off + fn * 16 + lq * 4;
            float bv = bias[co];
            f32x4 v = acc[fn][fc];
            #pragma unroll
            for (int r2 = 0; r2 < 4; ++r2) {
                float f = v[r2] + bv;
                if (RELU) f = fmaxf(f, 0.f);
                v[r2] = f;
            }
            float* o = PADOUT ? (dst + (size_t)co * NNP + GUARD + n)
                              : (dst + (size_t)co * NN + n);
            *(f32x4*)o = v;
        }
    }
}

// ---------------------------------------------------------------- deform GEMM
// Pure streaming GEMM: C[co][n] = sum_K wrb[co][K] * S[k][n][ci], K = k*256+ci
__global__ __launch_bounds__(256) void gemm_deform(
    const short* __restrict__ S,              // bf16 [27][NN][256]
    const short* __restrict__ wrb,            // bf16 c3d weights repacked
    const float* __restrict__ bias, float* __restrict__ out)
{
    __shared__ short Ap[64 * LDA];
    __shared__ short Bw[64 * LDA];
    const int tid = threadIdx.x;
    const int lane = tid & 63, wave = tid >> 6;
    const int n0 = blockIdx.x * 64, co0 = blockIdx.y * 64;
    const int n_l = tid & 63, grp = tid >> 6;
    const int co_l = tid >> 2, ch = tid & 3;
    const int n_off = (wave & 1) * 32, co_off = (wave >> 1) * 32;
    const int lm = lane & 15, lq = lane >> 4;

    f32x4 acc[2][2] = {};
    const short* bbase = wrb + (size_t)(co0 + co_l) * KDIM + ch * 16;
    const short* abase = S + (size_t)(n0 + n_l) * 256;

    for (int kt = 0; kt < KTILES; ++kt) {
        const int k = kt >> 2, ci0 = (kt & 3) * 64;
        {
            const short8* g = (const short8*)(abase + (size_t)k * NN * 256 + ci0 + grp * 16);
            short8 p0 = g[0], p1 = g[1];
            short8* dA = (short8*)&Ap[n_l * LDA + grp * 16];
            dA[0] = p0; dA[1] = p1;
        }
        {
            const short8* g = (const short8*)(bbase + (size_t)kt * BK);
            short8 b0 = g[0], b1 = g[1];
            short8* dB = (short8*)&Bw[co_l * LDA + ch * 16];
            dB[0] = b0; dB[1] = b1;
        }
        __syncthreads();
        #pragma unroll
        for (int ks = 0; ks < 2; ++ks) {
            short8 a0 = *(const short8*)&Ap[(n_off + lm) * LDA + ks * 32 + lq * 8];
            short8 a1 = *(const short8*)&Ap[(n_off + 16 + lm) * LDA + ks * 32 + lq * 8];
            short8 b0 = *(const short8*)&Bw[(co_off + lm) * LDA + ks * 32 + lq * 8];
            short8 b1 = *(const short8*)&Bw[(co_off + 16 + lm) * LDA + ks * 32 + lq * 8];
            acc[0][0] = MFMA16(a0, b0, acc[0][0], 0, 0, 0);
            acc[0][1] = MFMA16(a0, b1, acc[0][1], 0, 0, 0);
            acc[1][0] = MFMA16(a1, b0, acc[1][0], 0, 0, 0);
            acc[1][1] = MFMA16(a1, b1, acc[1][1], 0, 0, 0);
        }
        __syncthreads();
    }
    #pragma unroll
    for (int fn = 0; fn < 2; ++fn)
    #pragma unroll
    for (int fc = 0; fc < 2; ++fc) {
        int co = co0 + co_off + fc * 16 + lm;
        int n = n0 + n_off + fn * 16 + lq * 4;
        float bv = bias[co];
        f32x4 v = acc[fn][fc];
        #pragma unroll
        for (int r2 = 0; r2 < 4; ++r2) v[r2] += bv;
        *(f32x4*)(out + (size_t)co * NN + n) = v;
    }
}

// ----------------------------------------------------------------
extern "C" void kernel_launch(void* const* d_in, const int* in_sizes, int n_in,
                              void* d_out, int out_size, void* d_ws, size_t ws_size,
                              hipStream_t stream)
{
    const float* x   = (const float*)d_in[0];
    const float* l1w = (const float*)d_in[1];
    const float* l1b = (const float*)d_in[2];
    const float* l2w = (const float*)d_in[3];
    const float* l2b = (const float*)d_in[4];
    const float* l3w = (const float*)d_in[5];
    const float* l3b = (const float*)d_in[6];
    const float* dfw = (const float*)d_in[7];
    const float* dfb = (const float*)d_in[8];
    const float* c3w = (const float*)d_in[9];
    const float* c3b = (const float*)d_in[10];
    float* out = (float*)d_out;

    char* p = (char*)d_ws;
    short* S    = (short*)p; p += (size_t)27 * NN * 256 * 2;   // 63.7 MB
    float* xT   = (float*)p; p += (size_t)NN * 256 * 4;        // 4.7 MB
    float* xpad = (float*)p; p += (size_t)CIN * NNP * 4;
    float* h1   = (float*)p; p += (size_t)CIN * NNP * 4;
    float* h2   = (float*)p; p += (size_t)CIN * NNP * 4;
    float* h3   = (float*)p; p += (size_t)CIN * NNP * 4;
    short* wrb1 = (short*)p; p += (size_t)CIN * KDIM * 2;
    short* wrb2 = (short*)p; p += (size_t)CIN * KDIM * 2;
    short* wrb3 = (short*)p; p += (size_t)CIN * KDIM * 2;
    short* wrbc = (short*)p; p += (size_t)CIN * KDIM * 2;
    short* wrbd = (short*)p; p += (size_t)128 * KDIM * 2;      // 81 rows used, rest 0
    float* offs = (float*)p; p += (size_t)81 * NN * 4;
    unsigned long long* m64 = (unsigned long long*)p;

    // zero the pads of xpad/h1/h2/h3 (interiors are fully overwritten)
    hipMemsetAsync(xpad, 0, (size_t)4 * CIN * NNP * 4, stream);

    pad_copy_k<<<dim3(CIN * NN / 256), dim3(256), 0, stream>>>(x, xpad);
    transpose_k<<<dim3(72, 4), dim3(256), 0, stream>>>(x, xT);
    repack_w_k<<<dim3(256), dim3(256), 0, stream>>>(l1w, wrb1, 256);
    repack_w_k<<<dim3(256), dim3(256), 0, stream>>>(l2w, wrb2, 256);
    repack_w_k<<<dim3(256), dim3(256), 0, stream>>>(l3w, wrb3, 256);
    repack_w_k<<<dim3(256), dim3(256), 0, stream>>>(c3w, wrbc, 256);
    repack_w_k<<<dim3(128), dim3(256), 0, stream>>>(dfw, wrbd, 81);
    mask_k<<<dim3(8), dim3(256), 0, stream>>>(m64);

    gemm_conv<true,  true ><<<dim3(72, 4), dim3(256), 0, stream>>>(xpad, wrb1, m64, l1b, h1, 256);
    gemm_conv<true,  true ><<<dim3(72, 4), dim3(256), 0, stream>>>(h1,   wrb2, m64, l2b, h2, 256);
    gemm_conv<true,  true ><<<dim3(72, 4), dim3(256), 0, stream>>>(h2,   wrb3, m64, l3b, h3, 256);
    gemm_conv<false, false><<<dim3(72, 2), dim3(256), 0, stream>>>(h3,   wrbd, m64, dfb, offs, 81);

    sample_k<<<dim3(72, 27), dim3(256), 0, stream>>>(xT, offs, S);
    gemm_deform<<<dim3(72, 4), dim3(256), 0, stream>>>(S, wrbc, c3b, out);
}

// Round 4
// 340.029 us; speedup vs baseline: 21.4478x; 1.6529x over previous
//
#include <hip/hip_runtime.h>

#define TT 8
#define HH 24
#define WW 24
#define NN 4608            // T*H*W
#define CIN 256
#define GUARD 640          // >= max |tap shift| (601), multiple of 16
#define NNP (NN + 2*GUARD) // padded spatial row: 5888
#define KDIM 6912          // 27 taps * 256 ci
#define BK 64
#define KTILES 108         // KDIM / BK
#define NSPLIT 4
#define KT_PER 27          // KTILES / NSPLIT

typedef short short8 __attribute__((ext_vector_type(8)));
typedef short short4v __attribute__((ext_vector_type(4)));
typedef float f32x4  __attribute__((ext_vector_type(4)));
typedef unsigned long long ull;

#define MFMA16 __builtin_amdgcn_mfma_f32_16x16x32_bf16

__device__ __forceinline__ short f2bf(float f) {       // RNE f32 -> bf16 bits
    unsigned u = __float_as_uint(f);
    unsigned r = u + 0x7fffu + ((u >> 16) & 1u);
    return (short)(r >> 16);
}

// ---------------------------------------------------------------- utility
__global__ void pad_copy_k(const float* __restrict__ x, float* __restrict__ xp) {
    int gid = blockIdx.x * 256 + threadIdx.x;           // 256*NN threads
    int ci = gid / NN, n = gid - ci * NN;
    xp[(size_t)ci * NNP + GUARD + n] = x[gid];
}

// x[ci][n] -> xT[n][ci]
__global__ __launch_bounds__(256) void transpose_k(const float* __restrict__ x,
                                                   float* __restrict__ xT) {
    __shared__ float T[64][65];
    const int lane = threadIdx.x & 63, wave = threadIdx.x >> 6;
    const int n0 = blockIdx.x * 64, ci0 = blockIdx.y * 64;
    #pragma unroll
    for (int j = 0; j < 16; ++j) {
        int ci_l = wave * 16 + j;
        T[ci_l][lane] = x[(size_t)(ci0 + ci_l) * NN + n0 + lane];
    }
    __syncthreads();
    #pragma unroll
    for (int j = 0; j < 16; ++j) {
        int n_l = wave * 16 + j;
        xT[(size_t)(n0 + n_l) * 256 + ci0 + lane] = T[lane][n_l];
    }
}

// wrb[o][k*256+ci] = bf16(w[o][ci][k]); rows o>=Cout zeroed.
__global__ void repack_w_k(const float* __restrict__ w, short* __restrict__ dst, int Cout) {
    int o = blockIdx.x, ci = threadIdx.x;
    short* drow = dst + (size_t)o * KDIM + ci;
    if (o < Cout) {
        const float* src = w + ((size_t)o * CIN + ci) * 27;
        #pragma unroll
        for (int k = 0; k < 27; ++k) drow[(size_t)k * CIN] = f2bf(src[k]);
    } else {
        #pragma unroll
        for (int k = 0; k < 27; ++k) drow[(size_t)k * CIN] = 0;
    }
}

// mask64[k][wn]: bit b = tap k valid at spatial point n = wn*64+b
__global__ void mask_k(ull* __restrict__ m) {
    int id = blockIdx.x * 256 + threadIdx.x;
    if (id >= 27 * 72) return;
    int k = id / 72, wn = id - k * 72;
    int dt = k / 9 - 1, dh = (k % 9) / 3 - 1, dw = k % 3 - 1;
    ull word = 0;
    for (int b = 0; b < 64; ++b) {
        int n = wn * 64 + b;
        int t = n / (HH * WW), r = n % (HH * WW), h = r / WW, w2 = r % WW;
        int tt = t + dt, hh = h + dh, ww = w2 + dw;
        if (tt >= 0 && tt < TT && hh >= 0 && hh < HH && ww >= 0 && ww < WW)
            word |= 1ull << b;
    }
    m[id] = word;
}

// ---------------------------------------------------------------- sampler
__global__ __launch_bounds__(256) void sample_k(
    const float* __restrict__ xT, const float* __restrict__ offs,
    short* __restrict__ S)
{
    const int k = blockIdx.y, n0 = blockIdx.x * 64;
    const int lane = threadIdx.x & 63, wave = threadIdx.x >> 6;
    const int ki = k / 9, kj = (k % 9) / 3, kl = k % 3;

    for (int i = 0; i < 16; ++i) {
        const int n = n0 + wave * 16 + i;
        const int t = n / (HH * WW), r = n % (HH * WW), h = r / WW, w2 = r % WW;
        const float pt = (float)(t  + ki - 1) + offs[(size_t)(k * 3 + 0) * NN + n];
        const float ph = (float)(h  + kj - 1) + offs[(size_t)(k * 3 + 1) * NN + n];
        const float pw = (float)(w2 + kl - 1) + offs[(size_t)(k * 3 + 2) * NN + n];
        const float ft = floorf(pt), fh = floorf(ph), fw = floorf(pw);
        const float at = pt - ft, ah = ph - fh, aw = pw - fw;
        const int it = (int)ft, ih = (int)fh, iw = (int)fw;

        f32x4 s = {0.f, 0.f, 0.f, 0.f};
        #pragma unroll
        for (int dt = 0; dt < 2; ++dt)
        #pragma unroll
        for (int dh = 0; dh < 2; ++dh)
        #pragma unroll
        for (int dw = 0; dw < 2; ++dw) {
            const int ti = it + dt, hi = ih + dh, wi = iw + dw;
            const bool v = (ti >= 0) && (ti < TT) && (hi >= 0) && (hi < HH) && (wi >= 0) && (wi < WW);
            float wgt = (dt ? at : 1.f - at) * (dh ? ah : 1.f - ah) * (dw ? aw : 1.f - aw);
            wgt = v ? wgt : 0.f;
            const int tc = min(max(ti, 0), TT - 1), hc = min(max(hi, 0), HH - 1), wc = min(max(wi, 0), WW - 1);
            const int idx = (tc * HH + hc) * WW + wc;
            const f32x4 vv = *(const f32x4*)(xT + (size_t)idx * 256 + lane * 4);
            #pragma unroll
            for (int q = 0; q < 4; ++q) s[q] = fmaf(wgt, vv[q], s[q]);
        }
        short4v o;
        #pragma unroll
        for (int q = 0; q < 4; ++q) o[q] = f2bf(s[q]);
        *(short4v*)(S + ((size_t)k * NN + n) * 256 + lane * 4) = o;
    }
}

// ---------------------------------------------------------------- conv GEMM (split-K)
// Partial: P[split][co][n] = sum_{K in chunk} wrb[co][K] * patch[K][n]
template<int CP>
__global__ __launch_bounds__(256) void gemm_conv_sk(
    const float* __restrict__ src,            // padded [CIN][NNP]
    const short* __restrict__ wrb,            // bf16 [Cpad][KDIM], K = k*256+ci
    const ull* __restrict__ mask64,
    float* __restrict__ P)
{
    __shared__ short Ap[64 * 64];
    __shared__ short Bw[64 * 64];
    const int tid = threadIdx.x;
    const int lane = tid & 63, wave = tid >> 6;
    const int n0 = blockIdx.x * 64, co0 = blockIdx.y * 64, split = blockIdx.z;
    const int n_l = tid & 63, grp = tid >> 6;     // A-stage: 1 n x 16 ci
    const int co_l = tid >> 2, ch = tid & 3;      // B-stage: 1 co x 16 kk
    const int n_off = (wave & 1) * 32, co_off = (wave >> 1) * 32;
    const int lm = lane & 15, lq = lane >> 4;

    f32x4 acc[2][2] = {};

    const float* abase = src + GUARD + n0 + n_l;
    const short* bbase = wrb + (size_t)(co0 + co_l) * KDIM + ch * 16;
    const int wA = n_l * 64 + ((grp * 16) ^ ((n_l & 7) << 3));     // swizzled write idx
    const int wB = co_l * 64 + ((ch * 16) ^ ((co_l & 7) << 3));
    const int rswz = (lm & 7) << 3;

    for (int i = 0; i < KT_PER; ++i) {
        const int kt = split * KT_PER + i;
        const int k = kt >> 2, ci0 = (kt & 3) * 64;
        const int dt = k / 9 - 1, dh = (k % 9) / 3 - 1, dw = k % 3 - 1;
        const int delta = (dt * HH + dh) * WW + dw;
        const ull word = mask64[k * 72 + blockIdx.x];
        const bool keep = (word >> n_l) & 1;
        {
            const float* s0 = abase + delta + (size_t)(ci0 + grp * 16) * NNP;
            short8 p0, p1;
            #pragma unroll
            for (int j = 0; j < 8; ++j) p0[j] = f2bf(keep ? s0[(size_t)j * NNP] : 0.f);
            #pragma unroll
            for (int j = 0; j < 8; ++j) p1[j] = f2bf(keep ? s0[(size_t)(j + 8) * NNP] : 0.f);
            *(short8*)&Ap[wA] = p0;
            *(short8*)&Ap[wA ^ 8] = p1;
        }
        {
            const short8* g = (const short8*)(bbase + (size_t)kt * BK);
            short8 b0 = g[0], b1 = g[1];
            *(short8*)&Bw[wB] = b0;
            *(short8*)&Bw[wB ^ 8] = b1;
        }
        __syncthreads();
        #pragma unroll
        for (int ks = 0; ks < 2; ++ks) {
            const int c = (ks * 32 + lq * 8) ^ rswz;
            short8 a0 = *(const short8*)&Ap[(n_off + lm) * 64 + c];
            short8 a1 = *(const short8*)&Ap[(n_off + 16 + lm) * 64 + c];
            short8 b0 = *(const short8*)&Bw[(co_off + lm) * 64 + c];
            short8 b1 = *(const short8*)&Bw[(co_off + 16 + lm) * 64 + c];
            acc[0][0] = MFMA16(a0, b0, acc[0][0], 0, 0, 0);
            acc[0][1] = MFMA16(a0, b1, acc[0][1], 0, 0, 0);
            acc[1][0] = MFMA16(a1, b0, acc[1][0], 0, 0, 0);
            acc[1][1] = MFMA16(a1, b1, acc[1][1], 0, 0, 0);
        }
        __syncthreads();
    }
    #pragma unroll
    for (int fn = 0; fn < 2; ++fn)
    #pragma unroll
    for (int fc = 0; fc < 2; ++fc) {
        int co = co0 + co_off + fc * 16 + lm;
        int n = n0 + n_off + fn * 16 + lq * 4;
        *(f32x4*)(P + ((size_t)split * CP + co) * NN + n) = acc[fn][fc];
    }
}

// ---------------------------------------------------------------- deform GEMM (split-K)
__global__ __launch_bounds__(256) void gemm_deform_sk(
    const short* __restrict__ S,              // bf16 [27][NN][256]
    const short* __restrict__ wrb,
    float* __restrict__ P)
{
    __shared__ short Ap[64 * 64];
    __shared__ short Bw[64 * 64];
    const int tid = threadIdx.x;
    const int lane = tid & 63, wave = tid >> 6;
    const int n0 = blockIdx.x * 64, co0 = blockIdx.y * 64, split = blockIdx.z;
    const int n_l = tid & 63, grp = tid >> 6;
    const int co_l = tid >> 2, ch = tid & 3;
    const int n_off = (wave & 1) * 32, co_off = (wave >> 1) * 32;
    const int lm = lane & 15, lq = lane >> 4;

    f32x4 acc[2][2] = {};
    const short* bbase = wrb + (size_t)(co0 + co_l) * KDIM + ch * 16;
    const short* abase = S + (size_t)(n0 + n_l) * 256;
    const int wA = n_l * 64 + ((grp * 16) ^ ((n_l & 7) << 3));
    const int wB = co_l * 64 + ((ch * 16) ^ ((co_l & 7) << 3));
    const int rswz = (lm & 7) << 3;

    for (int i = 0; i < KT_PER; ++i) {
        const int kt = split * KT_PER + i;
        const int k = kt >> 2, ci0 = (kt & 3) * 64;
        {
            const short8* g = (const short8*)(abase + (size_t)k * NN * 256 + ci0 + grp * 16);
            short8 p0 = g[0], p1 = g[1];
            *(short8*)&Ap[wA] = p0;
            *(short8*)&Ap[wA ^ 8] = p1;
        }
        {
            const short8* g = (const short8*)(bbase + (size_t)kt * BK);
            short8 b0 = g[0], b1 = g[1];
            *(short8*)&Bw[wB] = b0;
            *(short8*)&Bw[wB ^ 8] = b1;
        }
        __syncthreads();
        #pragma unroll
        for (int ks = 0; ks < 2; ++ks) {
            const int c = (ks * 32 + lq * 8) ^ rswz;
            short8 a0 = *(const short8*)&Ap[(n_off + lm) * 64 + c];
            short8 a1 = *(const short8*)&Ap[(n_off + 16 + lm) * 64 + c];
            short8 b0 = *(const short8*)&Bw[(co_off + lm) * 64 + c];
            short8 b1 = *(const short8*)&Bw[(co_off + 16 + lm) * 64 + c];
            acc[0][0] = MFMA16(a0, b0, acc[0][0], 0, 0, 0);
            acc[0][1] = MFMA16(a0, b1, acc[0][1], 0, 0, 0);
            acc[1][0] = MFMA16(a1, b0, acc[1][0], 0, 0, 0);
            acc[1][1] = MFMA16(a1, b1, acc[1][1], 0, 0, 0);
        }
        __syncthreads();
    }
    #pragma unroll
    for (int fn = 0; fn < 2; ++fn)
    #pragma unroll
    for (int fc = 0; fc < 2; ++fc) {
        int co = co0 + co_off + fc * 16 + lm;
        int n = n0 + n_off + fn * 16 + lq * 4;
        *(f32x4*)(P + ((size_t)split * 256 + co) * NN + n) = acc[fn][fc];
    }
}

// ---------------------------------------------------------------- reduce (bias/relu/pad fused)
template<bool RELU, bool PADOUT>
__global__ __launch_bounds__(256) void reduce_k(
    const float* __restrict__ P, const float* __restrict__ bias,
    float* __restrict__ dst, int Cout, int CP)
{
    int id = blockIdx.x * 256 + threadIdx.x;          // one f32x4 each
    int total = Cout * (NN / 4);
    if (id >= total) return;
    int co = id / (NN / 4), n4 = id - co * (NN / 4);
    const float* p0 = P + ((size_t)co) * NN + n4 * 4;
    f32x4 v = *(const f32x4*)p0;
    #pragma unroll
    for (int s = 1; s < NSPLIT; ++s) {
        f32x4 u = *(const f32x4*)(p0 + (size_t)s * CP * NN);
        #pragma unroll
        for (int q = 0; q < 4; ++q) v[q] += u[q];
    }
    float bv = bias[co];
    #pragma unroll
    for (int q = 0; q < 4; ++q) {
        float f = v[q] + bv;
        if (RELU) f = fmaxf(f, 0.f);
        v[q] = f;
    }
    float* o = PADOUT ? (dst + (size_t)co * NNP + GUARD + n4 * 4)
                      : (dst + (size_t)co * NN + n4 * 4);
    *(f32x4*)o = v;
}

// ----------------------------------------------------------------
extern "C" void kernel_launch(void* const* d_in, const int* in_sizes, int n_in,
                              void* d_out, int out_size, void* d_ws, size_t ws_size,
                              hipStream_t stream)
{
    const float* x   = (const float*)d_in[0];
    const float* l1w = (const float*)d_in[1];
    const float* l1b = (const float*)d_in[2];
    const float* l2w = (const float*)d_in[3];
    const float* l2b = (const float*)d_in[4];
    const float* l3w = (const float*)d_in[5];
    const float* l3b = (const float*)d_in[6];
    const float* dfw = (const float*)d_in[7];
    const float* dfb = (const float*)d_in[8];
    const float* c3w = (const float*)d_in[9];
    const float* c3b = (const float*)d_in[10];
    float* out = (float*)d_out;

    // ---- workspace layout with S overlaying buffers dead before sample_k ----
    char* base = (char*)d_ws;
    // overlay region [0, 63.7MB): S (written at sample_k) over conv-phase buffers
    short* S    = (short*)base;                              // 27*NN*256*2 = 63,700,992
    float* xpad = (float*)(base);                            // 6,029,312
    float* h1   = (float*)(base + 6029312);                  // 6,029,312
    float* h2   = (float*)(base + 12058624);
    float* h3   = (float*)(base + 18087936);
    short* wrb1 = (short*)(base + 24117248);                 // 3,538,944
    short* wrb2 = (short*)(base + 27656192);
    short* wrb3 = (short*)(base + 31195136);
    short* wrbd = (short*)(base + 34734080);                 // 1,769,472
    ull*   m64  = (ull*)  (base + 36503552);                 // 15,552
    // non-overlaid region:
    char* q = base + 63700992;
    float* offs = (float*)q; q += 1492992;                   // 81*NN*4
    float* xT   = (float*)q; q += 4718592;                   // NN*256*4
    short* wrbc = (short*)q; q += 3538944;                   // 256*KDIM*2
    float* P    = (float*)q;                                 // 4*256*NN*4 = 18,874,368

    // zero the pads of xpad/h1/h2/h3 (interiors fully overwritten each call)
    hipMemsetAsync(xpad, 0, (size_t)4 * CIN * NNP * 4, stream);

    pad_copy_k<<<dim3(CIN * NN / 256), dim3(256), 0, stream>>>(x, xpad);
    transpose_k<<<dim3(72, 4), dim3(256), 0, stream>>>(x, xT);
    repack_w_k<<<dim3(256), dim3(256), 0, stream>>>(l1w, wrb1, 256);
    repack_w_k<<<dim3(256), dim3(256), 0, stream>>>(l2w, wrb2, 256);
    repack_w_k<<<dim3(256), dim3(256), 0, stream>>>(l3w, wrb3, 256);
    repack_w_k<<<dim3(256), dim3(256), 0, stream>>>(c3w, wrbc, 256);
    repack_w_k<<<dim3(128), dim3(256), 0, stream>>>(dfw, wrbd, 81);
    mask_k<<<dim3(8), dim3(256), 0, stream>>>(m64);

    const dim3 blk(256);
    const int rg256 = (256 * (NN / 4) + 255) / 256;   // 1152
    const int rg81  = (81  * (NN / 4) + 255) / 256;   // 365

    gemm_conv_sk<256><<<dim3(72, 4, NSPLIT), blk, 0, stream>>>(xpad, wrb1, m64, P);
    reduce_k<true,  true ><<<dim3(rg256), blk, 0, stream>>>(P, l1b, h1, 256, 256);
    gemm_conv_sk<256><<<dim3(72, 4, NSPLIT), blk, 0, stream>>>(h1, wrb2, m64, P);
    reduce_k<true,  true ><<<dim3(rg256), blk, 0, stream>>>(P, l2b, h2, 256, 256);
    gemm_conv_sk<256><<<dim3(72, 4, NSPLIT), blk, 0, stream>>>(h2, wrb3, m64, P);
    reduce_k<true,  true ><<<dim3(rg256), blk, 0, stream>>>(P, l3b, h3, 256, 256);
    gemm_conv_sk<128><<<dim3(72, 2, NSPLIT), blk, 0, stream>>>(h3, wrbd, m64, P);
    reduce_k<false, false><<<dim3(rg81),  blk, 0, stream>>>(P, dfb, offs, 81, 128);

    sample_k<<<dim3(72, 27), blk, 0, stream>>>(xT, offs, S);
    gemm_deform_sk<<<dim3(72, 4, NSPLIT), blk, 0, stream>>>(S, wrbc, P);
    reduce_k<false, false><<<dim3(rg256), blk, 0, stream>>>(P, c3b, out, 256, 256);
}

// Round 5
// 314.719 us; speedup vs baseline: 23.1727x; 1.0804x over previous
//
#include <hip/hip_runtime.h>

#define TT 8
#define HH 24
#define WW 24
#define NN 4608            // T*H*W
#define CIN 256
#define N3 6760            // padded volume 10*26*26 (bf16 transposed layout rows)
#define KDIM 6912          // 27 taps * 256 ci
#define BK 64
#define KTILES 108         // KDIM / BK
#define NSPLIT 4
#define KT_PER 27          // KTILES / NSPLIT

typedef short short8 __attribute__((ext_vector_type(8)));
typedef short short4v __attribute__((ext_vector_type(4)));
typedef float f32x4  __attribute__((ext_vector_type(4)));

#define MFMA16 __builtin_amdgcn_mfma_f32_16x16x32_bf16

__device__ __forceinline__ short f2bf(float f) {       // RNE f32 -> bf16 bits
    unsigned u = __float_as_uint(f);
    unsigned r = u + 0x7fffu + ((u >> 16) & 1u);
    return (short)(r >> 16);
}

__device__ __forceinline__ int n3_of(int n) {          // interior n -> padded row
    int t = n / (HH * WW), r = n % (HH * WW), h = r / WW, w = r % WW;
    return ((t + 1) * 26 + (h + 1)) * 26 + (w + 1);
}

// ---------------------------------------------------------------- utility
// x[ci][n] -> xT[n][ci] (f32, for sampler) and xbf3[n3][ci] (bf16 padded, for conv1)
__global__ __launch_bounds__(256) void transpose_k(const float* __restrict__ x,
                                                   float* __restrict__ xT,
                                                   short* __restrict__ xbf3) {
    __shared__ float T[64][65];
    const int lane = threadIdx.x & 63, wave = threadIdx.x >> 6;
    const int n0 = blockIdx.x * 64, ci0 = blockIdx.y * 64;
    #pragma unroll
    for (int j = 0; j < 16; ++j) {
        int ci_l = wave * 16 + j;
        T[ci_l][lane] = x[(size_t)(ci0 + ci_l) * NN + n0 + lane];
    }
    __syncthreads();
    #pragma unroll
    for (int j = 0; j < 16; ++j) {
        int n_l = wave * 16 + j;
        float v = T[lane][n_l];
        xT[(size_t)(n0 + n_l) * 256 + ci0 + lane] = v;
        xbf3[(size_t)n3_of(n0 + n_l) * 256 + ci0 + lane] = f2bf(v);
    }
}

// wrb[o][k*256+ci] = bf16(w[o][ci][k]); rows o>=Cout zeroed.
__global__ void repack_w_k(const float* __restrict__ w, short* __restrict__ dst, int Cout) {
    int o = blockIdx.x, ci = threadIdx.x;
    short* drow = dst + (size_t)o * KDIM + ci;
    if (o < Cout) {
        const float* src = w + ((size_t)o * CIN + ci) * 27;
        #pragma unroll
        for (int k = 0; k < 27; ++k) drow[(size_t)k * CIN] = f2bf(src[k]);
    } else {
        #pragma unroll
        for (int k = 0; k < 27; ++k) drow[(size_t)k * CIN] = 0;
    }
}

// ---------------------------------------------------------------- sampler
__global__ __launch_bounds__(256) void sample_k(
    const float* __restrict__ xT, const float* __restrict__ offs,
    short* __restrict__ S)
{
    const int k = blockIdx.y, n0 = blockIdx.x * 64;
    const int lane = threadIdx.x & 63, wave = threadIdx.x >> 6;
    const int ki = k / 9, kj = (k % 9) / 3, kl = k % 3;

    for (int i = 0; i < 16; ++i) {
        const int n = n0 + wave * 16 + i;
        const int t = n / (HH * WW), r = n % (HH * WW), h = r / WW, w2 = r % WW;
        const float pt = (float)(t  + ki - 1) + offs[(size_t)(k * 3 + 0) * NN + n];
        const float ph = (float)(h  + kj - 1) + offs[(size_t)(k * 3 + 1) * NN + n];
        const float pw = (float)(w2 + kl - 1) + offs[(size_t)(k * 3 + 2) * NN + n];
        const float ft = floorf(pt), fh = floorf(ph), fw = floorf(pw);
        const float at = pt - ft, ah = ph - fh, aw = pw - fw;
        const int it = (int)ft, ih = (int)fh, iw = (int)fw;

        f32x4 s = {0.f, 0.f, 0.f, 0.f};
        #pragma unroll
        for (int dt = 0; dt < 2; ++dt)
        #pragma unroll
        for (int dh = 0; dh < 2; ++dh)
        #pragma unroll
        for (int dw = 0; dw < 2; ++dw) {
            const int ti = it + dt, hi = ih + dh, wi = iw + dw;
            const bool v = (ti >= 0) && (ti < TT) && (hi >= 0) && (hi < HH) && (wi >= 0) && (wi < WW);
            float wgt = (dt ? at : 1.f - at) * (dh ? ah : 1.f - ah) * (dw ? aw : 1.f - aw);
            wgt = v ? wgt : 0.f;
            const int tc = min(max(ti, 0), TT - 1), hc = min(max(hi, 0), HH - 1), wc = min(max(wi, 0), WW - 1);
            const int idx = (tc * HH + hc) * WW + wc;
            const f32x4 vv = *(const f32x4*)(xT + (size_t)idx * 256 + lane * 4);
            #pragma unroll
            for (int q = 0; q < 4; ++q) s[q] = fmaf(wgt, vv[q], s[q]);
        }
        short4v o;
        #pragma unroll
        for (int q = 0; q < 4; ++q) o[q] = f2bf(s[q]);
        *(short4v*)(S + ((size_t)k * NN + n) * 256 + lane * 4) = o;
    }
}

// ---------------------------------------------------------------- conv GEMM (split-K, bf16 3D-padded input)
// P[split][co][n] = sum_{K chunk} wrb[co][k*256+ci] * src[n3(n)+delta3(k)][ci]
template<int CP>
__global__ __launch_bounds__(256) void gemm_conv_sk(
    const short* __restrict__ src,            // bf16 [N3][256]
    const short* __restrict__ wrb,            // bf16 [Cpad][KDIM]
    float* __restrict__ P)
{
    __shared__ short Ap[64 * 64];
    __shared__ short Bw[64 * 64];
    const int tid = threadIdx.x;
    const int lane = tid & 63, wave = tid >> 6;
    const int n0 = blockIdx.x * 64, co0 = blockIdx.y * 64, split = blockIdx.z;
    const int n_l = tid & 63, grp = tid >> 6;     // A-stage: 1 n x 16 ci
    const int co_l = tid >> 2, ch = tid & 3;      // B-stage: 1 co x 16 kk
    const int n_off = (wave & 1) * 32, co_off = (wave >> 1) * 32;
    const int lm = lane & 15, lq = lane >> 4;

    f32x4 acc[2][2] = {};

    const int r3 = n3_of(n0 + n_l);               // this thread's padded row
    const short* bbase = wrb + (size_t)(co0 + co_l) * KDIM + ch * 16;
    const int wA = n_l * 64 + ((grp * 16) ^ ((n_l & 7) << 3));     // swizzled write idx
    const int wB = co_l * 64 + ((ch * 16) ^ ((co_l & 7) << 3));
    const int rswz = (lm & 7) << 3;

    for (int i = 0; i < KT_PER; ++i) {
        const int kt = split * KT_PER + i;
        const int k = kt >> 2, ci0 = (kt & 3) * 64;
        const int dt = k / 9 - 1, dh = (k % 9) / 3 - 1, dw = k % 3 - 1;
        const int d3 = (dt * 26 + dh) * 26 + dw;
        {
            const short8* g = (const short8*)(src + (size_t)(r3 + d3) * 256 + ci0 + grp * 16);
            short8 p0 = g[0], p1 = g[1];
            *(short8*)&Ap[wA] = p0;
            *(short8*)&Ap[wA ^ 8] = p1;
        }
        {
            const short8* g = (const short8*)(bbase + (size_t)kt * BK);
            short8 b0 = g[0], b1 = g[1];
            *(short8*)&Bw[wB] = b0;
            *(short8*)&Bw[wB ^ 8] = b1;
        }
        __syncthreads();
        #pragma unroll
        for (int ks = 0; ks < 2; ++ks) {
            const int c = (ks * 32 + lq * 8) ^ rswz;
            short8 a0 = *(const short8*)&Ap[(n_off + lm) * 64 + c];
            short8 a1 = *(const short8*)&Ap[(n_off + 16 + lm) * 64 + c];
            short8 b0 = *(const short8*)&Bw[(co_off + lm) * 64 + c];
            short8 b1 = *(const short8*)&Bw[(co_off + 16 + lm) * 64 + c];
            acc[0][0] = MFMA16(a0, b0, acc[0][0], 0, 0, 0);
            acc[0][1] = MFMA16(a0, b1, acc[0][1], 0, 0, 0);
            acc[1][0] = MFMA16(a1, b0, acc[1][0], 0, 0, 0);
            acc[1][1] = MFMA16(a1, b1, acc[1][1], 0, 0, 0);
        }
        __syncthreads();
    }
    #pragma unroll
    for (int fn = 0; fn < 2; ++fn)
    #pragma unroll
    for (int fc = 0; fc < 2; ++fc) {
        int co = co0 + co_off + fc * 16 + lm;
        int n = n0 + n_off + fn * 16 + lq * 4;
        *(f32x4*)(P + ((size_t)split * CP + co) * NN + n) = acc[fn][fc];
    }
}

// ---------------------------------------------------------------- deform GEMM (split-K)
__global__ __launch_bounds__(256) void gemm_deform_sk(
    const short* __restrict__ S,              // bf16 [27][NN][256]
    const short* __restrict__ wrb,
    float* __restrict__ P)
{
    __shared__ short Ap[64 * 64];
    __shared__ short Bw[64 * 64];
    const int tid = threadIdx.x;
    const int lane = tid & 63, wave = tid >> 6;
    const int n0 = blockIdx.x * 64, co0 = blockIdx.y * 64, split = blockIdx.z;
    const int n_l = tid & 63, grp = tid >> 6;
    const int co_l = tid >> 2, ch = tid & 3;
    const int n_off = (wave & 1) * 32, co_off = (wave >> 1) * 32;
    const int lm = lane & 15, lq = lane >> 4;

    f32x4 acc[2][2] = {};
    const short* bbase = wrb + (size_t)(co0 + co_l) * KDIM + ch * 16;
    const short* abase = S + (size_t)(n0 + n_l) * 256;
    const int wA = n_l * 64 + ((grp * 16) ^ ((n_l & 7) << 3));
    const int wB = co_l * 64 + ((ch * 16) ^ ((co_l & 7) << 3));
    const int rswz = (lm & 7) << 3;

    for (int i = 0; i < KT_PER; ++i) {
        const int kt = split * KT_PER + i;
        const int k = kt >> 2, ci0 = (kt & 3) * 64;
        {
            const short8* g = (const short8*)(abase + (size_t)k * NN * 256 + ci0 + grp * 16);
            short8 p0 = g[0], p1 = g[1];
            *(short8*)&Ap[wA] = p0;
            *(short8*)&Ap[wA ^ 8] = p1;
        }
        {
            const short8* g = (const short8*)(bbase + (size_t)kt * BK);
            short8 b0 = g[0], b1 = g[1];
            *(short8*)&Bw[wB] = b0;
            *(short8*)&Bw[wB ^ 8] = b1;
        }
        __syncthreads();
        #pragma unroll
        for (int ks = 0; ks < 2; ++ks) {
            const int c = (ks * 32 + lq * 8) ^ rswz;
            short8 a0 = *(const short8*)&Ap[(n_off + lm) * 64 + c];
            short8 a1 = *(const short8*)&Ap[(n_off + 16 + lm) * 64 + c];
            short8 b0 = *(const short8*)&Bw[(co_off + lm) * 64 + c];
            short8 b1 = *(const short8*)&Bw[(co_off + 16 + lm) * 64 + c];
            acc[0][0] = MFMA16(a0, b0, acc[0][0], 0, 0, 0);
            acc[0][1] = MFMA16(a0, b1, acc[0][1], 0, 0, 0);
            acc[1][0] = MFMA16(a1, b0, acc[1][0], 0, 0, 0);
            acc[1][1] = MFMA16(a1, b1, acc[1][1], 0, 0, 0);
        }
        __syncthreads();
    }
    #pragma unroll
    for (int fn = 0; fn < 2; ++fn)
    #pragma unroll
    for (int fc = 0; fc < 2; ++fc) {
        int co = co0 + co_off + fc * 16 + lm;
        int n = n0 + n_off + fn * 16 + lq * 4;
        *(f32x4*)(P + ((size_t)split * 256 + co) * NN + n) = acc[fn][fc];
    }
}

// ---------------------------------------------------------------- reduces
// f32 flat output (offs, final out)
template<bool RELU>
__global__ __launch_bounds__(256) void reduce_k(
    const float* __restrict__ P, const float* __restrict__ bias,
    float* __restrict__ dst, int Cout, int CP)
{
    int id = blockIdx.x * 256 + threadIdx.x;
    int total = Cout * (NN / 4);
    if (id >= total) return;
    int co = id / (NN / 4), n4 = id - co * (NN / 4);
    const float* p0 = P + ((size_t)co) * NN + n4 * 4;
    f32x4 v = *(const f32x4*)p0;
    #pragma unroll
    for (int s = 1; s < NSPLIT; ++s) {
        f32x4 u = *(const f32x4*)(p0 + (size_t)s * CP * NN);
        #pragma unroll
        for (int q = 0; q < 4; ++q) v[q] += u[q];
    }
    float bv = bias[co];
    #pragma unroll
    for (int q = 0; q < 4; ++q) {
        float f = v[q] + bv;
        if (RELU) f = fmaxf(f, 0.f);
        v[q] = f;
    }
    *(f32x4*)(dst + (size_t)co * NN + n4 * 4) = v;
}

// bf16 3D-padded transposed output (h layers): bias+relu+cvt+transpose fused
__global__ __launch_bounds__(256) void reduce_bf3(
    const float* __restrict__ P, const float* __restrict__ bias,
    short* __restrict__ dst)
{
    __shared__ float T[64][65];
    const int lane = threadIdx.x & 63, wave = threadIdx.x >> 6;
    const int n0 = blockIdx.x * 64, co0 = blockIdx.y * 64;
    #pragma unroll
    for (int j = 0; j < 16; ++j) {
        int co_l = wave * 16 + j, co = co0 + co_l;
        const float* p0 = P + (size_t)co * NN + n0 + lane;
        float a = p0[0];
        #pragma unroll
        for (int s = 1; s < NSPLIT; ++s) a += p0[(size_t)s * 256 * NN];
        T[co_l][lane] = fmaxf(a + bias[co], 0.f);
    }
    __syncthreads();
    #pragma unroll
    for (int j = 0; j < 16; ++j) {
        int n_l = wave * 16 + j;
        dst[(size_t)n3_of(n0 + n_l) * 256 + co0 + lane] = f2bf(T[lane][n_l]);
    }
}

// ----------------------------------------------------------------
extern "C" void kernel_launch(void* const* d_in, const int* in_sizes, int n_in,
                              void* d_out, int out_size, void* d_ws, size_t ws_size,
                              hipStream_t stream)
{
    const float* x   = (const float*)d_in[0];
    const float* l1w = (const float*)d_in[1];
    const float* l1b = (const float*)d_in[2];
    const float* l2w = (const float*)d_in[3];
    const float* l2b = (const float*)d_in[4];
    const float* l3w = (const float*)d_in[5];
    const float* l3b = (const float*)d_in[6];
    const float* dfw = (const float*)d_in[7];
    const float* dfb = (const float*)d_in[8];
    const float* c3w = (const float*)d_in[9];
    const float* c3b = (const float*)d_in[10];
    float* out = (float*)d_out;

    // ---- workspace: S (sample-phase) overlays all conv-phase buffers ----
    char* base = (char*)d_ws;
    short* S    = (short*)base;                              // 27*NN*256*2 = 63,700,992
    short* xbf3 = (short*)(base);                            // N3*256*2 = 3,461,120
    short* h1b  = (short*)(base + 3461120);
    short* h2b  = (short*)(base + 6922240);
    short* h3b  = (short*)(base + 10383360);
    short* wrb1 = (short*)(base + 13844480);                 // 3,538,944
    short* wrb2 = (short*)(base + 17383424);
    short* wrb3 = (short*)(base + 20922368);
    short* wrbd = (short*)(base + 24461312);                 // 1,769,472 (ends 26.2MB < 63.7MB)
    char* q = base + 63700992;                               // non-overlaid:
    float* offs = (float*)q; q += 1492992;                   // 81*NN*4
    float* xT   = (float*)q; q += 4718592;                   // NN*256*4
    short* wrbc = (short*)q; q += 3538944;                   // 256*KDIM*2
    float* P    = (float*)q;                                 // 4*256*NN*4 = 18,874,368

    // zero pads of the four bf16 3D-padded buffers (contiguous; interiors overwritten)
    hipMemsetAsync(xbf3, 0, (size_t)4 * N3 * 256 * 2, stream);

    transpose_k<<<dim3(72, 4), dim3(256), 0, stream>>>(x, xT, xbf3);
    repack_w_k<<<dim3(256), dim3(256), 0, stream>>>(l1w, wrb1, 256);
    repack_w_k<<<dim3(256), dim3(256), 0, stream>>>(l2w, wrb2, 256);
    repack_w_k<<<dim3(256), dim3(256), 0, stream>>>(l3w, wrb3, 256);
    repack_w_k<<<dim3(256), dim3(256), 0, stream>>>(c3w, wrbc, 256);
    repack_w_k<<<dim3(128), dim3(256), 0, stream>>>(dfw, wrbd, 81);

    const dim3 blk(256);
    const int rg256 = (256 * (NN / 4) + 255) / 256;   // 1152
    const int rg81  = (81  * (NN / 4) + 255) / 256;   // 365

    gemm_conv_sk<256><<<dim3(72, 4, NSPLIT), blk, 0, stream>>>(xbf3, wrb1, P);
    reduce_bf3       <<<dim3(72, 4),         blk, 0, stream>>>(P, l1b, h1b);
    gemm_conv_sk<256><<<dim3(72, 4, NSPLIT), blk, 0, stream>>>(h1b, wrb2, P);
    reduce_bf3       <<<dim3(72, 4),         blk, 0, stream>>>(P, l2b, h2b);
    gemm_conv_sk<256><<<dim3(72, 4, NSPLIT), blk, 0, stream>>>(h2b, wrb3, P);
    reduce_bf3       <<<dim3(72, 4),         blk, 0, stream>>>(P, l3b, h3b);
    gemm_conv_sk<128><<<dim3(72, 2, NSPLIT), blk, 0, stream>>>(h3b, wrbd, P);
    reduce_k<false>  <<<dim3(rg81),          blk, 0, stream>>>(P, dfb, offs, 81, 128);

    sample_k<<<dim3(72, 27), blk, 0, stream>>>(xT, offs, S);
    gemm_deform_sk<<<dim3(72, 4, NSPLIT), blk, 0, stream>>>(S, wrbc, P);
    reduce_k<false><<<dim3(rg256), blk, 0, stream>>>(P, c3b, out, 256, 256);
}

// Round 6
// 292.733 us; speedup vs baseline: 24.9132x; 1.0751x over previous
//
#include <hip/hip_runtime.h>

#define TT 8
#define HH 24
#define WW 24
#define NN 4608            // T*H*W
#define CIN 256
#define N3 6760            // padded volume 10*26*26 (bf16 transposed layout rows)
#define KDIM 6912          // 27 taps * 256 ci
#define BK 64
#define KTILES 108         // KDIM / BK
#define NSPLIT 4
#define KT_PER 27          // KTILES / NSPLIT

typedef short short8 __attribute__((ext_vector_type(8)));
typedef short short4v __attribute__((ext_vector_type(4)));
typedef float f32x4  __attribute__((ext_vector_type(4)));

#define MFMA16 __builtin_amdgcn_mfma_f32_16x16x32_bf16

__device__ __forceinline__ short f2bf(float f) {       // RNE f32 -> bf16 bits
    unsigned u = __float_as_uint(f);
    unsigned r = u + 0x7fffu + ((u >> 16) & 1u);
    return (short)(r >> 16);
}

__device__ __forceinline__ int n3_of(int n) {          // interior n -> padded row
    int t = n / (HH * WW), r = n % (HH * WW), h = r / WW, w = r % WW;
    return ((t + 1) * 26 + (h + 1)) * 26 + (w + 1);
}

// async 16B global -> LDS (wave-uniform LDS base + lane*16; global addr per-lane)
__device__ __forceinline__ void gload16(const void* gsrc, void* lds) {
    __builtin_amdgcn_global_load_lds(
        (const __attribute__((address_space(1))) void*)gsrc,
        (__attribute__((address_space(3))) void*)lds, 16, 0, 0);
}

// ---------------------------------------------------------------- utility
// x[ci][n] -> xT[n][ci] (f32, for sampler) and xbf3[n3][ci] (bf16 padded, for conv1)
__global__ __launch_bounds__(256) void transpose_k(const float* __restrict__ x,
                                                   float* __restrict__ xT,
                                                   short* __restrict__ xbf3) {
    __shared__ float T[64][65];
    const int lane = threadIdx.x & 63, wave = threadIdx.x >> 6;
    const int n0 = blockIdx.x * 64, ci0 = blockIdx.y * 64;
    #pragma unroll
    for (int j = 0; j < 16; ++j) {
        int ci_l = wave * 16 + j;
        T[ci_l][lane] = x[(size_t)(ci0 + ci_l) * NN + n0 + lane];
    }
    __syncthreads();
    #pragma unroll
    for (int j = 0; j < 16; ++j) {
        int n_l = wave * 16 + j;
        float v = T[lane][n_l];
        xT[(size_t)(n0 + n_l) * 256 + ci0 + lane] = v;
        xbf3[(size_t)n3_of(n0 + n_l) * 256 + ci0 + lane] = f2bf(v);
    }
}

// Pre-swizzled weight repack for linear global_load_lds staging.
// Layout: wrb_sw[y][kt][slot=row*8+g'][e], g' = (kk>>3) ^ (row&7), row=o&63, y=o>>6.
__global__ void repack_w_k(const float* __restrict__ w, short* __restrict__ dst, int Cout) {
    int o = blockIdx.x, ci = threadIdx.x;
    const int row = o & 63, y = o >> 6;
    #pragma unroll
    for (int k = 0; k < 27; ++k) {
        int K = k * 256 + ci;
        int kt = K >> 6, kk = K & 63;
        int g = (kk >> 3) ^ (row & 7), e = kk & 7;
        size_t idx = (((size_t)y * KTILES + kt) * 512 + row * 8 + g) * 8 + e;
        float v = (o < Cout) ? w[((size_t)o * CIN + ci) * 27 + k] : 0.f;
        dst[idx] = f2bf(v);
    }
}

// ---------------------------------------------------------------- sampler
__global__ __launch_bounds__(256) void sample_k(
    const float* __restrict__ xT, const float* __restrict__ offs,
    short* __restrict__ S)
{
    const int k = blockIdx.y, n0 = blockIdx.x * 64;
    const int lane = threadIdx.x & 63, wave = threadIdx.x >> 6;
    const int ki = k / 9, kj = (k % 9) / 3, kl = k % 3;

    for (int i = 0; i < 16; ++i) {
        const int n = n0 + wave * 16 + i;
        const int t = n / (HH * WW), r = n % (HH * WW), h = r / WW, w2 = r % WW;
        const float pt = (float)(t  + ki - 1) + offs[(size_t)(k * 3 + 0) * NN + n];
        const float ph = (float)(h  + kj - 1) + offs[(size_t)(k * 3 + 1) * NN + n];
        const float pw = (float)(w2 + kl - 1) + offs[(size_t)(k * 3 + 2) * NN + n];
        const float ft = floorf(pt), fh = floorf(ph), fw = floorf(pw);
        const float at = pt - ft, ah = ph - fh, aw = pw - fw;
        const int it = (int)ft, ih = (int)fh, iw = (int)fw;

        f32x4 s = {0.f, 0.f, 0.f, 0.f};
        #pragma unroll
        for (int dt = 0; dt < 2; ++dt)
        #pragma unroll
        for (int dh = 0; dh < 2; ++dh)
        #pragma unroll
        for (int dw = 0; dw < 2; ++dw) {
            const int ti = it + dt, hi = ih + dh, wi = iw + dw;
            const bool v = (ti >= 0) && (ti < TT) && (hi >= 0) && (hi < HH) && (wi >= 0) && (wi < WW);
            float wgt = (dt ? at : 1.f - at) * (dh ? ah : 1.f - ah) * (dw ? aw : 1.f - aw);
            wgt = v ? wgt : 0.f;
            const int tc = min(max(ti, 0), TT - 1), hc = min(max(hi, 0), HH - 1), wc = min(max(wi, 0), WW - 1);
            const int idx = (tc * HH + hc) * WW + wc;
            const f32x4 vv = *(const f32x4*)(xT + (size_t)idx * 256 + lane * 4);
            #pragma unroll
            for (int q = 0; q < 4; ++q) s[q] = fmaf(wgt, vv[q], s[q]);
        }
        short4v o;
        #pragma unroll
        for (int q = 0; q < 4; ++q) o[q] = f2bf(s[q]);
        *(short4v*)(S + ((size_t)k * NN + n) * 256 + lane * 4) = o;
    }
}

// ---------------------------------------------------------------- conv GEMM (split-K, async 2-phase pipeline)
// P[split][co][n] = sum_{K chunk} wrb[co][k*256+ci] * src[n3(n)+delta3(k)][ci]
template<int CP>
__global__ __launch_bounds__(256) void gemm_conv_sk(
    const short* __restrict__ src,            // bf16 [N3][256] plain
    const short* __restrict__ wrb_sw,         // bf16 pre-swizzled [y][kt][512][8]
    float* __restrict__ P)
{
    __shared__ short Ap[2][4096];
    __shared__ short Bw[2][4096];
    const int tid = threadIdx.x;
    const int l = tid & 63, w = tid >> 6;
    const int n0 = blockIdx.x * 64, co0 = blockIdx.y * 64, split = blockIdx.z;
    const int n_off = (w & 1) * 32, co_off = (w >> 1) * 32;
    const int lm = l & 15, lq = l >> 4;
    const int rswz = (lm & 7) << 3;
    const int kt0 = split * KT_PER;

    // staging geometry: load i of wave w covers rows w*16+i*8+(l>>3), col group (l&7)^(l>>3)
    const int colA = 8 * ((l & 7) ^ (l >> 3));
    const int r3A0 = n3_of(n0 + w * 16 + (l >> 3));
    const int r3A1 = n3_of(n0 + w * 16 + 8 + (l >> 3));
    const short* bbase = wrb_sw + ((size_t)blockIdx.y * KTILES) * 4096 + (w * 2) * 512 + l * 8;

    f32x4 acc[2][2] = {};

    auto stage = [&](int buf, int kt) {
        const int k = kt >> 2, ci0 = (kt & 3) * 64;
        const int dt = k / 9 - 1, dh = (k % 9) / 3 - 1, dw = k % 3 - 1;
        const int d3 = (dt * 26 + dh) * 26 + dw;
        gload16(src + (size_t)(r3A0 + d3) * 256 + ci0 + colA, &Ap[buf][(w * 2) * 512]);
        gload16(src + (size_t)(r3A1 + d3) * 256 + ci0 + colA, &Ap[buf][(w * 2 + 1) * 512]);
        const short* b = bbase + (size_t)kt * 4096;
        gload16(b,       &Bw[buf][(w * 2) * 512]);
        gload16(b + 512, &Bw[buf][(w * 2 + 1) * 512]);
    };

    int cur = 0;
    stage(0, kt0);
    __syncthreads();
    for (int i = 0; i < KT_PER; ++i) {
        if (i + 1 < KT_PER) stage(cur ^ 1, kt0 + i + 1);
        #pragma unroll
        for (int ks = 0; ks < 2; ++ks) {
            const int c = (ks * 32 + lq * 8) ^ rswz;
            short8 a0 = *(const short8*)&Ap[cur][(n_off + lm) * 64 + c];
            short8 a1 = *(const short8*)&Ap[cur][(n_off + 16 + lm) * 64 + c];
            short8 b0 = *(const short8*)&Bw[cur][(co_off + lm) * 64 + c];
            short8 b1 = *(const short8*)&Bw[cur][(co_off + 16 + lm) * 64 + c];
            acc[0][0] = MFMA16(a0, b0, acc[0][0], 0, 0, 0);
            acc[0][1] = MFMA16(a0, b1, acc[0][1], 0, 0, 0);
            acc[1][0] = MFMA16(a1, b0, acc[1][0], 0, 0, 0);
            acc[1][1] = MFMA16(a1, b1, acc[1][1], 0, 0, 0);
        }
        __syncthreads();   // drains vmcnt(0): next tile's stage complete; lgkm: reads done
        cur ^= 1;
    }
    #pragma unroll
    for (int fn = 0; fn < 2; ++fn)
    #pragma unroll
    for (int fc = 0; fc < 2; ++fc) {
        int co = co0 + co_off + fc * 16 + lm;
        int n = n0 + n_off + fn * 16 + lq * 4;
        *(f32x4*)(P + ((size_t)split * CP + co) * NN + n) = acc[fn][fc];
    }
}

// ---------------------------------------------------------------- deform GEMM (split-K, async 2-phase pipeline)
__global__ __launch_bounds__(256) void gemm_deform_sk(
    const short* __restrict__ S,              // bf16 [27][NN][256] plain
    const short* __restrict__ wrb_sw,
    float* __restrict__ P)
{
    __shared__ short Ap[2][4096];
    __shared__ short Bw[2][4096];
    const int tid = threadIdx.x;
    const int l = tid & 63, w = tid >> 6;
    const int n0 = blockIdx.x * 64, co0 = blockIdx.y * 64, split = blockIdx.z;
    const int n_off = (w & 1) * 32, co_off = (w >> 1) * 32;
    const int lm = l & 15, lq = l >> 4;
    const int rswz = (lm & 7) << 3;
    const int kt0 = split * KT_PER;

    const int colA = 8 * ((l & 7) ^ (l >> 3));
    const int rA0 = n0 + w * 16 + (l >> 3);
    const int rA1 = rA0 + 8;
    const short* bbase = wrb_sw + ((size_t)blockIdx.y * KTILES) * 4096 + (w * 2) * 512 + l * 8;

    f32x4 acc[2][2] = {};

    auto stage = [&](int buf, int kt) {
        const int k = kt >> 2, ci0 = (kt & 3) * 64;
        gload16(S + ((size_t)k * NN + rA0) * 256 + ci0 + colA, &Ap[buf][(w * 2) * 512]);
        gload16(S + ((size_t)k * NN + rA1) * 256 + ci0 + colA, &Ap[buf][(w * 2 + 1) * 512]);
        const short* b = bbase + (size_t)kt * 4096;
        gload16(b,       &Bw[buf][(w * 2) * 512]);
        gload16(b + 512, &Bw[buf][(w * 2 + 1) * 512]);
    };

    int cur = 0;
    stage(0, kt0);
    __syncthreads();
    for (int i = 0; i < KT_PER; ++i) {
        if (i + 1 < KT_PER) stage(cur ^ 1, kt0 + i + 1);
        #pragma unroll
        for (int ks = 0; ks < 2; ++ks) {
            const int c = (ks * 32 + lq * 8) ^ rswz;
            short8 a0 = *(const short8*)&Ap[cur][(n_off + lm) * 64 + c];
            short8 a1 = *(const short8*)&Ap[cur][(n_off + 16 + lm) * 64 + c];
            short8 b0 = *(const short8*)&Bw[cur][(co_off + lm) * 64 + c];
            short8 b1 = *(const short8*)&Bw[cur][(co_off + 16 + lm) * 64 + c];
            acc[0][0] = MFMA16(a0, b0, acc[0][0], 0, 0, 0);
            acc[0][1] = MFMA16(a0, b1, acc[0][1], 0, 0, 0);
            acc[1][0] = MFMA16(a1, b0, acc[1][0], 0, 0, 0);
            acc[1][1] = MFMA16(a1, b1, acc[1][1], 0, 0, 0);
        }
        __syncthreads();
        cur ^= 1;
    }
    #pragma unroll
    for (int fn = 0; fn < 2; ++fn)
    #pragma unroll
    for (int fc = 0; fc < 2; ++fc) {
        int co = co0 + co_off + fc * 16 + lm;
        int n = n0 + n_off + fn * 16 + lq * 4;
        *(f32x4*)(P + ((size_t)split * 256 + co) * NN + n) = acc[fn][fc];
    }
}

// ---------------------------------------------------------------- reduces
// f32 flat output (offs, final out)
template<bool RELU>
__global__ __launch_bounds__(256) void reduce_k(
    const float* __restrict__ P, const float* __restrict__ bias,
    float* __restrict__ dst, int Cout, int CP)
{
    int id = blockIdx.x * 256 + threadIdx.x;
    int total = Cout * (NN / 4);
    if (id >= total) return;
    int co = id / (NN / 4), n4 = id - co * (NN / 4);
    const float* p0 = P + ((size_t)co) * NN + n4 * 4;
    f32x4 v = *(const f32x4*)p0;
    #pragma unroll
    for (int s = 1; s < NSPLIT; ++s) {
        f32x4 u = *(const f32x4*)(p0 + (size_t)s * CP * NN);
        #pragma unroll
        for (int q = 0; q < 4; ++q) v[q] += u[q];
    }
    float bv = bias[co];
    #pragma unroll
    for (int q = 0; q < 4; ++q) {
        float f = v[q] + bv;
        if (RELU) f = fmaxf(f, 0.f);
        v[q] = f;
    }
    *(f32x4*)(dst + (size_t)co * NN + n4 * 4) = v;
}

// bf16 3D-padded transposed output (h layers): bias+relu+cvt+transpose fused
__global__ __launch_bounds__(256) void reduce_bf3(
    const float* __restrict__ P, const float* __restrict__ bias,
    short* __restrict__ dst)
{
    __shared__ float T[64][65];
    const int lane = threadIdx.x & 63, wave = threadIdx.x >> 6;
    const int n0 = blockIdx.x * 64, co0 = blockIdx.y * 64;
    #pragma unroll
    for (int j = 0; j < 16; ++j) {
        int co_l = wave * 16 + j, co = co0 + co_l;
        const float* p0 = P + (size_t)co * NN + n0 + lane;
        float a = p0[0];
        #pragma unroll
        for (int s = 1; s < NSPLIT; ++s) a += p0[(size_t)s * 256 * NN];
        T[co_l][lane] = fmaxf(a + bias[co], 0.f);
    }
    __syncthreads();
    #pragma unroll
    for (int j = 0; j < 16; ++j) {
        int n_l = wave * 16 + j;
        dst[(size_t)n3_of(n0 + n_l) * 256 + co0 + lane] = f2bf(T[lane][n_l]);
    }
}

// ----------------------------------------------------------------
extern "C" void kernel_launch(void* const* d_in, const int* in_sizes, int n_in,
                              void* d_out, int out_size, void* d_ws, size_t ws_size,
                              hipStream_t stream)
{
    const float* x   = (const float*)d_in[0];
    const float* l1w = (const float*)d_in[1];
    const float* l1b = (const float*)d_in[2];
    const float* l2w = (const float*)d_in[3];
    const float* l2b = (const float*)d_in[4];
    const float* l3w = (const float*)d_in[5];
    const float* l3b = (const float*)d_in[6];
    const float* dfw = (const float*)d_in[7];
    const float* dfb = (const float*)d_in[8];
    const float* c3w = (const float*)d_in[9];
    const float* c3b = (const float*)d_in[10];
    float* out = (float*)d_out;

    // ---- workspace: S (sample-phase) overlays all conv-phase buffers ----
    char* base = (char*)d_ws;
    short* S    = (short*)base;                              // 27*NN*256*2 = 63,700,992
    short* xbf3 = (short*)(base);                            // N3*256*2 = 3,461,120
    short* h1b  = (short*)(base + 3461120);
    short* h2b  = (short*)(base + 6922240);
    short* h3b  = (short*)(base + 10383360);
    short* wrb1 = (short*)(base + 13844480);                 // 3,538,944
    short* wrb2 = (short*)(base + 17383424);
    short* wrb3 = (short*)(base + 20922368);
    short* wrbd = (short*)(base + 24461312);                 // 1,769,472 (ends 26.2MB < 63.7MB)
    char* q = base + 63700992;                               // non-overlaid:
    float* offs = (float*)q; q += 1492992;                   // 81*NN*4
    float* xT   = (float*)q; q += 4718592;                   // NN*256*4
    short* wrbc = (short*)q; q += 3538944;                   // 256*KDIM*2
    float* P    = (float*)q;                                 // 4*256*NN*4 = 18,874,368

    // zero pads of the four bf16 3D-padded buffers (contiguous; interiors overwritten)
    hipMemsetAsync(xbf3, 0, (size_t)4 * N3 * 256 * 2, stream);

    transpose_k<<<dim3(72, 4), dim3(256), 0, stream>>>(x, xT, xbf3);
    repack_w_k<<<dim3(256), dim3(256), 0, stream>>>(l1w, wrb1, 256);
    repack_w_k<<<dim3(256), dim3(256), 0, stream>>>(l2w, wrb2, 256);
    repack_w_k<<<dim3(256), dim3(256), 0, stream>>>(l3w, wrb3, 256);
    repack_w_k<<<dim3(256), dim3(256), 0, stream>>>(c3w, wrbc, 256);
    repack_w_k<<<dim3(128), dim3(256), 0, stream>>>(dfw, wrbd, 81);

    const dim3 blk(256);
    const int rg256 = (256 * (NN / 4) + 255) / 256;   // 1152
    const int rg81  = (81  * (NN / 4) + 255) / 256;   // 365

    gemm_conv_sk<256><<<dim3(72, 4, NSPLIT), blk, 0, stream>>>(xbf3, wrb1, P);
    reduce_bf3       <<<dim3(72, 4),         blk, 0, stream>>>(P, l1b, h1b);
    gemm_conv_sk<256><<<dim3(72, 4, NSPLIT), blk, 0, stream>>>(h1b, wrb2, P);
    reduce_bf3       <<<dim3(72, 4),         blk, 0, stream>>>(P, l2b, h2b);
    gemm_conv_sk<256><<<dim3(72, 4, NSPLIT), blk, 0, stream>>>(h2b, wrb3, P);
    reduce_bf3       <<<dim3(72, 4),         blk, 0, stream>>>(P, l3b, h3b);
    gemm_conv_sk<128><<<dim3(72, 2, NSPLIT), blk, 0, stream>>>(h3b, wrbd, P);
    reduce_k<false>  <<<dim3(rg81),          blk, 0, stream>>>(P, dfb, offs, 81, 128);

    sample_k<<<dim3(72, 27), blk, 0, stream>>>(xT, offs, S);
    gemm_deform_sk<<<dim3(72, 4, NSPLIT), blk, 0, stream>>>(S, wrbc, P);
    reduce_k<false><<<dim3(rg256), blk, 0, stream>>>(P, c3b, out, 256, 256);
}